// Round 6
// baseline (320.084 us; speedup 1.0000x reference)
//
#include <hip/hip_runtime.h>
#include <stdint.h>

#define NROWS 16384
#define NC    10000
#define NF4   2500              // float4 per row
#define BLK   256
#define WPB   4                 // waves per block, one row per wave
#define NBLK  (NROWS / WPB)     // 4096 blocks
#define NCELL 256               // spread cells for the fixed-point sum
#define EPSF  1e-7f
#define SCALE 262144.0          // 2^18 fixed-point

struct U2 { uint32_t a, b; };

// JAX Threefry-2x32 (20 rounds), exactly as jax/_src/prng.py.
__host__ __device__ constexpr U2 tf2x32(uint32_t k0, uint32_t k1,
                                        uint32_t x0, uint32_t x1) {
  const uint32_t ks2 = k0 ^ k1 ^ 0x1BD11BDAu;
  uint32_t v0 = x0 + k0, v1 = x1 + k1;
#define TF_R(r) { v0 += v1; v1 = (v1 << (r)) | (v1 >> (32 - (r))); v1 ^= v0; }
  TF_R(13) TF_R(15) TF_R(26) TF_R(6)
  v0 += k1;  v1 += ks2 + 1u;
  TF_R(17) TF_R(29) TF_R(16) TF_R(24)
  v0 += ks2; v1 += k0 + 2u;
  TF_R(13) TF_R(15) TF_R(26) TF_R(6)
  v0 += k0;  v1 += k1 + 3u;
  TF_R(17) TF_R(29) TF_R(16) TF_R(24)
  v0 += k1;  v1 += ks2 + 4u;
  TF_R(13) TF_R(15) TF_R(26) TF_R(6)
  v0 += ks2; v1 += k0 + 5u;
#undef TF_R
  return {v0, v1};
}

constexpr U2 KA = tf2x32(0u, 42u, 0u, 0u);   // k_off (key(42) split, compile-time)
constexpr U2 KB = tf2x32(0u, 42u, 0u, 1u);   // k_u

// ws layout (unsigned long long): ws[0] = block counter; ws[1..NCELL] = cells
__global__ __launch_bounds__(BLK, 8)
void nnce_rows(const float* __restrict__ pred,
               const int* __restrict__ labels,
               float* __restrict__ out,              // out[0]=loss, out[1+i]=norm_i
               unsigned long long* __restrict__ ws)
{
  __shared__ long long lred[WPB];
  __shared__ int lflag;

  const int tid  = threadIdx.x;
  const int lane = tid & 63;
  const int wid  = tid >> 6;
  const int row  = blockIdx.x * WPB + wid;
  const float*  p  = pred + (size_t)row * NC;
  const float4* p4 = (const float4*)p;

  // ---- early per-row scalars: label, RNG (3 hashes on 3 lanes, uniform CF) ----
  const int lab = labels[row];
  const uint32_t xin = (uint32_t)row + ((lane == 1) ? (uint32_t)NROWS : 0u);
  const uint32_t kk0 = (lane == 2) ? KB.a : KA.a;
  const uint32_t kk1 = (lane == 2) ? KB.b : KA.b;
  const U2 rr = tf2x32(kk0, kk1, 0u, xin);
  const uint32_t hb  = __shfl((int)rr.b, 0, 64);   // higher randint bits
  const uint32_t lob = __shfl((int)rr.b, 1, 64);   // lower randint bits
  const uint32_t ub  = __shfl((int)rr.b, 2, 64);   // uniform bits
  const uint32_t span = 9999u, mult = 6835u;       // (2^16 % 9999)^2 % 9999
  const uint32_t off = ((hb % span) * mult + (lob % span)) % span;
  const float ru = __uint_as_float((ub >> 9) | 0x3F800000u) - 1.0f;
  const int cand1 = (lab + 1 + (int)off) % NC;     // randint(1,C)-shifted label != lab
  const float p_lab = p[lab];                       // issued before the stream
  const float p_c1  = p[cand1];

  // ---- single streaming pass: moments sp,ss,sc,sq + max (no index!) ----
  float sp = 0.f, ss = 0.f, sc = 0.f, sq = 0.f, mv = -1e30f;

#define PROC1(xv) { const float q_ = (xv) * (xv);               \
    sp += (xv); ss += q_;                                        \
    sc = fmaf(q_, (xv), sc); sq = fmaf(q_, q_, sq);              \
    mv = fmaxf(mv, (xv)); }
#define PROC4(v) { PROC1((v).x); PROC1((v).y); PROC1((v).z); PROC1((v).w); }

  int k = lane;
#pragma unroll 1
  for (int it = 0; it < 9; ++it) {            // 9 x 4 = 36 float4 per lane
    const float4 a = p4[k], b = p4[k + 64], c = p4[k + 128], d = p4[k + 192];
    PROC4(a); PROC4(b); PROC4(c); PROC4(d);
    k += 256;
  }
  {                                           // 3 more: k = lane + 2304
    const float4 a = p4[k], b = p4[k + 64], c = p4[k + 128];
    PROC4(a); PROC4(b); PROC4(c);
  }
  if (lane < 4) {                             // ragged tail: 2500 = 39*64 + 4
    const float4 t = p4[2496 + lane];
    PROC4(t);
  }
#undef PROC4
#undef PROC1

  // ---- butterfly reduce (no LDS, no barrier) ----
  for (int o = 32; o > 0; o >>= 1) {
    sp += __shfl_xor(sp, o, 64);
    ss += __shfl_xor(ss, o, 64);
    sc += __shfl_xor(sc, o, 64);
    sq += __shfl_xor(sq, o, 64);
    mv  = fmaxf(mv, __shfl_xor(mv, o, 64));
  }

  // ---- epilogue (uniform across the wave) ----
  const float norm  = sqrtf(ss) + EPSF;
  const float inv2n = 0.5f / norm;
  const float i2    = inv2n * inv2n;
  // Z = sum exp(x), Zm = sum exp(-x), Taylor in moments (|x| <= ~0.05):
  const float t1 = sp * inv2n;
  const float t2 = 0.5f * ss * i2;
  const float t3 = (1.0f / 6.0f) * sc * i2 * inv2n;
  const float t4 = (1.0f / 24.0f) * sq * i2 * i2;
  const float Z    = (float)NC + t1 + t2 + t3 + t4;
  const float Zm   = (float)NC - t1 + t2 - t3 + t4;
  const float logZ = logf(Z);
  const float eZ   = EPSF * Z;

  const float max_prob = __expf(mv * inv2n) / Z + EPSF;
  // amax == lab  <=>  p[lab] attains the row max (ties measure-zero for normals)
  const bool  replace  = (ru <= max_prob) && (mv != p_lab);
  const float p_neg    = replace ? mv : p_c1;      // p[amax] == mv when replaced

  // log(snorm_j + eps) = x_j + log1p(eZ e^{-x_j}) - logZ ~= x_j + eZ(1 - x_j) - logZ
  const float x_lab  = p_lab * inv2n;
  const float x_neg  = p_neg * inv2n;
  const float ls_lab = x_lab + eZ * (1.0f - x_lab) - logZ;
  const float ls_neg = x_neg + eZ * (1.0f - x_neg) - logZ;
  const float sumlog = t1 + eZ * Zm - (float)NC * logZ;   // sum_j log(snorm_j+eps)

  const float val = (sumlog - ls_lab) - ls_neg;

  if (lane == 0) {
    out[1 + row] = norm;
    // deterministic fixed-point accumulation (integer adds commute)
    const long long fx = (long long)((double)val * SCALE);
    atomicAdd(&ws[1 + (blockIdx.x & (NCELL - 1))], (unsigned long long)fx);
  }

  // ---- last-block final reduction ----
  __syncthreads();                 // all 4 waves' atomics issued (program order per lane0)
  if (tid == 0) {
    __threadfence();
    const unsigned long long old = atomicAdd(&ws[0], 1ULL);
    lflag = (old == (unsigned long long)(NBLK - 1)) ? 1 : 0;
  }
  __syncthreads();
  if (lflag) {
    long long v = 0;
    if (tid < NCELL) v = (long long)atomicAdd(&ws[1 + tid], 0ULL);  // coherent read
    for (int o = 32; o > 0; o >>= 1) v += __shfl_down(v, o, 64);
    if (lane == 0) lred[wid] = v;
    __syncthreads();
    if (tid == 0) {
      long long t = 0;
      for (int w = 0; w < WPB; ++w) t += lred[w];
      out[0] = (float)(10.0 * ((double)t / SCALE) / (double)NROWS);
    }
  }
}

extern "C" void kernel_launch(void* const* d_in, const int* in_sizes, int n_in,
                              void* d_out, int out_size, void* d_ws, size_t ws_size,
                              hipStream_t stream) {
  const float* pred   = (const float*)d_in[0];
  const int*   labels = (const int*)d_in[1];
  float* out = (float*)d_out;
  unsigned long long* ws = (unsigned long long*)d_ws;

  hipMemsetAsync(d_ws, 0, (1 + NCELL) * sizeof(unsigned long long), stream);
  nnce_rows<<<NBLK, BLK, 0, stream>>>(pred, labels, out, ws);
}

// Round 7
// 145.253 us; speedup vs baseline: 2.2036x; 2.2036x over previous
//
#include <hip/hip_runtime.h>
#include <stdint.h>

#define NROWS 16384
#define NC    10000
#define NF4   2500              // float4 per row
#define BLK   128               // 2 waves per block, one row per wave
#define WPB   2
#define NBLK  (NROWS / WPB)     // 8192 blocks -> 16 wg/CU * 2 waves = 32 waves/CU
#define EPSF  1e-7f

struct U2 { uint32_t a, b; };

// JAX Threefry-2x32 (20 rounds), exactly as jax/_src/prng.py.
__host__ __device__ constexpr U2 tf2x32(uint32_t k0, uint32_t k1,
                                        uint32_t x0, uint32_t x1) {
  const uint32_t ks2 = k0 ^ k1 ^ 0x1BD11BDAu;
  uint32_t v0 = x0 + k0, v1 = x1 + k1;
#define TF_R(r) { v0 += v1; v1 = (v1 << (r)) | (v1 >> (32 - (r))); v1 ^= v0; }
  TF_R(13) TF_R(15) TF_R(26) TF_R(6)
  v0 += k1;  v1 += ks2 + 1u;
  TF_R(17) TF_R(29) TF_R(16) TF_R(24)
  v0 += ks2; v1 += k0 + 2u;
  TF_R(13) TF_R(15) TF_R(26) TF_R(6)
  v0 += k0;  v1 += k1 + 3u;
  TF_R(17) TF_R(29) TF_R(16) TF_R(24)
  v0 += k1;  v1 += ks2 + 4u;
  TF_R(13) TF_R(15) TF_R(26) TF_R(6)
  v0 += ks2; v1 += k0 + 5u;
#undef TF_R
  return {v0, v1};
}

constexpr U2 KA = tf2x32(0u, 42u, 0u, 0u);   // k_off (key(42) split, compile-time)
constexpr U2 KB = tf2x32(0u, 42u, 0u, 1u);   // k_u

__global__ __launch_bounds__(BLK, 8)
void nnce_rows(const float* __restrict__ pred,
               const int* __restrict__ labels,
               float* __restrict__ out,       // out[0]=loss, out[1+i]=norm_i
               float* __restrict__ row_acc)   // per-row (pos - neg)
{
  const int tid  = threadIdx.x;
  const int lane = tid & 63;
  const int wid  = tid >> 6;
  const int row  = blockIdx.x * WPB + wid;
  const float*  p  = pred + (size_t)row * NC;
  const float4* p4 = (const float4*)p;

  // ---- early per-row scalars: label, RNG (3 hashes on 3 lanes, uniform CF) ----
  const int lab = labels[row];
  const uint32_t xin = (uint32_t)row + ((lane == 1) ? (uint32_t)NROWS : 0u);
  const uint32_t kk0 = (lane == 2) ? KB.a : KA.a;
  const uint32_t kk1 = (lane == 2) ? KB.b : KA.b;
  const U2 rr = tf2x32(kk0, kk1, 0u, xin);
  const uint32_t hb  = __shfl((int)rr.b, 0, 64);   // higher randint bits
  const uint32_t lob = __shfl((int)rr.b, 1, 64);   // lower randint bits
  const uint32_t ub  = __shfl((int)rr.b, 2, 64);   // uniform bits
  const uint32_t span = 9999u, mult = 6835u;       // (2^16 % 9999)^2 % 9999
  const uint32_t off = ((hb % span) * mult + (lob % span)) % span;
  const float ru = __uint_as_float((ub >> 9) | 0x3F800000u) - 1.0f;
  const int cand1 = (lab + 1 + (int)off) % NC;     // randint(1,C)-shifted label
  const float p_lab = p[lab];                       // issued before the stream
  const float p_c1  = p[cand1];

  // ---- single streaming pass, software-pipelined groups of 4 float4 ----
  float sp = 0.f, ss = 0.f, sc = 0.f, sq = 0.f, mv = -1e30f;

#define PROC1(xv) { const float q_ = (xv) * (xv);               \
    sp += (xv); ss += q_;                                        \
    sc = fmaf(q_, (xv), sc); sq = fmaf(q_, q_, sq);              \
    mv = fmaxf(mv, (xv)); }
#define PROC4(v) { PROC1((v).x); PROC1((v).y); PROC1((v).z); PROC1((v).w); }

  int k = lane;
  float4 c0 = p4[k], c1 = p4[k + 64], c2 = p4[k + 128], c3 = p4[k + 192];
#pragma unroll 1
  for (int it = 0; it < 8; ++it) {            // process g0..g7, prefetch g1..g8
    const float4 n0 = p4[k + 256], n1 = p4[k + 320],
                 n2 = p4[k + 384], n3 = p4[k + 448];
    PROC4(c0); PROC4(c1); PROC4(c2); PROC4(c3);
    c0 = n0; c1 = n1; c2 = n2; c3 = n3;
    k += 256;
  }
  // k = lane + 2048; c* = g8 (m=32..35). Prefetch last 3 + ragged tail, then drain.
  const float4 e0 = p4[k + 256], e1 = p4[k + 320], e2 = p4[k + 384]; // m=36..38
  float4 tl;
  const bool hast = (lane < 4);               // 2500 = 39*64 + 4
  if (hast) tl = p4[2496 + lane];
  PROC4(c0); PROC4(c1); PROC4(c2); PROC4(c3);
  PROC4(e0); PROC4(e1); PROC4(e2);
  if (hast) PROC4(tl);
#undef PROC4
#undef PROC1

  // ---- butterfly reduce (no LDS, no barrier) ----
  for (int o = 32; o > 0; o >>= 1) {
    sp += __shfl_xor(sp, o, 64);
    ss += __shfl_xor(ss, o, 64);
    sc += __shfl_xor(sc, o, 64);
    sq += __shfl_xor(sq, o, 64);
    mv  = fmaxf(mv, __shfl_xor(mv, o, 64));
  }

  // ---- epilogue (uniform across the wave) ----
  const float norm  = sqrtf(ss) + EPSF;
  const float inv2n = 0.5f / norm;
  const float i2    = inv2n * inv2n;
  // Z = sum exp(x), Zm = sum exp(-x), Taylor in moments (|x| <= ~0.05):
  const float t1 = sp * inv2n;
  const float t2 = 0.5f * ss * i2;
  const float t3 = (1.0f / 6.0f) * sc * i2 * inv2n;
  const float t4 = (1.0f / 24.0f) * sq * i2 * i2;
  const float Z    = (float)NC + t1 + t2 + t3 + t4;
  const float Zm   = (float)NC - t1 + t2 - t3 + t4;
  const float logZ = logf(Z);
  const float eZ   = EPSF * Z;

  const float max_prob = __expf(mv * inv2n) / Z + EPSF;
  // amax == lab  <=>  p[lab] attains the row max (ties measure-zero for normals)
  const bool  replace  = (ru <= max_prob) && (mv != p_lab);
  const float p_neg    = replace ? mv : p_c1;      // p[amax] == mv when replaced

  // log(snorm_j + eps) = x_j + log1p(eZ e^{-x_j}) - logZ ~= x_j + eZ(1 - x_j) - logZ
  const float x_lab  = p_lab * inv2n;
  const float x_neg  = p_neg * inv2n;
  const float ls_lab = x_lab + eZ * (1.0f - x_lab) - logZ;
  const float ls_neg = x_neg + eZ * (1.0f - x_neg) - logZ;
  const float sumlog = t1 + eZ * Zm - (float)NC * logZ;   // sum_j log(snorm_j+eps)

  if (lane == 0) {
    out[1 + row] = norm;
    row_acc[row] = (sumlog - ls_lab) - ls_neg;
  }
}

__global__ __launch_bounds__(512)
void nnce_final(const float* __restrict__ row_acc, float* __restrict__ out) {
  __shared__ double lred[8];
  const int tid  = threadIdx.x;
  const int lane = tid & 63;
  const int wid  = tid >> 6;
  const float4* r4 = (const float4*)row_acc;   // 4096 float4
  double s = 0.0;
  for (int i = tid; i < NROWS / 4; i += 512) {
    const float4 v = r4[i];
    s += (double)v.x + (double)v.y + (double)v.z + (double)v.w;
  }
  for (int o = 32; o > 0; o >>= 1) s += __shfl_xor(s, o, 64);
  if (lane == 0) lred[wid] = s;
  __syncthreads();
  if (tid == 0) {
    double t = 0.0;
    for (int w = 0; w < 8; ++w) t += lred[w];
    out[0] = (float)(10.0 * t / (double)NROWS);
  }
}

extern "C" void kernel_launch(void* const* d_in, const int* in_sizes, int n_in,
                              void* d_out, int out_size, void* d_ws, size_t ws_size,
                              hipStream_t stream) {
  const float* pred   = (const float*)d_in[0];
  const int*   labels = (const int*)d_in[1];
  float* out     = (float*)d_out;
  float* row_acc = (float*)d_ws;   // 64 KB

  nnce_rows<<<NBLK, BLK, 0, stream>>>(pred, labels, out, row_acc);
  nnce_final<<<1, 512, 0, stream>>>(row_acc, out);
}

// Round 8
// 121.613 us; speedup vs baseline: 2.6320x; 1.1944x over previous
//
#include <hip/hip_runtime.h>
#include <stdint.h>

#define NROWS 16384
#define NC    10000
#define NF4   2500              // float4 per row
#define BLK   256
#define WPB   4                 // waves per block, one row per wave
#define NBLK  (NROWS / WPB)     // 4096 blocks
#define EPSF  1e-7f

struct U2 { uint32_t a, b; };

// JAX Threefry-2x32 (20 rounds), exactly as jax/_src/prng.py.
__host__ __device__ constexpr U2 tf2x32(uint32_t k0, uint32_t k1,
                                        uint32_t x0, uint32_t x1) {
  const uint32_t ks2 = k0 ^ k1 ^ 0x1BD11BDAu;
  uint32_t v0 = x0 + k0, v1 = x1 + k1;
#define TF_R(r) { v0 += v1; v1 = (v1 << (r)) | (v1 >> (32 - (r))); v1 ^= v0; }
  TF_R(13) TF_R(15) TF_R(26) TF_R(6)
  v0 += k1;  v1 += ks2 + 1u;
  TF_R(17) TF_R(29) TF_R(16) TF_R(24)
  v0 += ks2; v1 += k0 + 2u;
  TF_R(13) TF_R(15) TF_R(26) TF_R(6)
  v0 += k0;  v1 += k1 + 3u;
  TF_R(17) TF_R(29) TF_R(16) TF_R(24)
  v0 += k1;  v1 += ks2 + 4u;
  TF_R(13) TF_R(15) TF_R(26) TF_R(6)
  v0 += ks2; v1 += k0 + 5u;
#undef TF_R
  return {v0, v1};
}

constexpr U2 KA = tf2x32(0u, 42u, 0u, 0u);   // k_off (key(42) split, compile-time)
constexpr U2 KB = tf2x32(0u, 42u, 0u, 1u);   // k_u

__global__ __launch_bounds__(BLK, 8)
void nnce_rows(const float* __restrict__ pred,
               const int* __restrict__ labels,
               float* __restrict__ out,       // out[0]=loss, out[1+i]=norm_i
               float* __restrict__ row_acc)   // per-row (pos - neg)
{
  const int tid  = threadIdx.x;
  const int lane = tid & 63;
  const int wid  = tid >> 6;
  const int row  = blockIdx.x * WPB + wid;
  const float*  p  = pred + (size_t)row * NC;
  const float4* p4 = (const float4*)p;

  // ---- early per-row scalars: label, RNG (3 hashes on 3 lanes, uniform CF) ----
  const int lab = labels[row];
  const uint32_t xin = (uint32_t)row + ((lane == 1) ? (uint32_t)NROWS : 0u);
  const uint32_t kk0 = (lane == 2) ? KB.a : KA.a;
  const uint32_t kk1 = (lane == 2) ? KB.b : KA.b;
  const U2 rr = tf2x32(kk0, kk1, 0u, xin);
  const uint32_t hb  = __shfl((int)rr.b, 0, 64);   // higher randint bits
  const uint32_t lob = __shfl((int)rr.b, 1, 64);   // lower randint bits
  const uint32_t ub  = __shfl((int)rr.b, 2, 64);   // uniform bits
  const uint32_t span = 9999u, mult = 6835u;       // (2^16 % 9999)^2 % 9999
  const uint32_t off = ((hb % span) * mult + (lob % span)) % span;
  const float ru = __uint_as_float((ub >> 9) | 0x3F800000u) - 1.0f;
  const int cand1 = (lab + 1 + (int)off) % NC;     // randint(1,C)-shifted label
  const float p_lab = p[lab];                       // issued before the stream
  const float p_c1  = p[cand1];

  // ---- single streaming pass: moments sp,ss,sc,sq + max (no index) ----
  float sp = 0.f, ss = 0.f, sc = 0.f, sq = 0.f, mv = -1e30f;

#define PROC1(xv) { const float q_ = (xv) * (xv);               \
    sp += (xv); ss += q_;                                        \
    sc = fmaf(q_, (xv), sc); sq = fmaf(q_, q_, sq);              \
    mv = fmaxf(mv, (xv)); }
#define PROC4(v) { PROC1((v).x); PROC1((v).y); PROC1((v).z); PROC1((v).w); }

  int k = lane;
#pragma unroll 1
  for (int it = 0; it < 9; ++it) {            // 9 x 4 = 36 float4 per lane
    const float4 a = p4[k], b = p4[k + 64], c = p4[k + 128], d = p4[k + 192];
    PROC4(a); PROC4(b); PROC4(c); PROC4(d);
    k += 256;
  }
  {                                           // 3 more: k = lane + 2304
    const float4 a = p4[k], b = p4[k + 64], c = p4[k + 128];
    PROC4(a); PROC4(b); PROC4(c);
  }
  if (lane < 4) {                             // ragged tail: 2500 = 39*64 + 4
    const float4 t = p4[2496 + lane];
    PROC4(t);
  }
#undef PROC4
#undef PROC1

  // ---- butterfly reduce (no LDS, no barrier) ----
  for (int o = 32; o > 0; o >>= 1) {
    sp += __shfl_xor(sp, o, 64);
    ss += __shfl_xor(ss, o, 64);
    sc += __shfl_xor(sc, o, 64);
    sq += __shfl_xor(sq, o, 64);
    mv  = fmaxf(mv, __shfl_xor(mv, o, 64));
  }

  // ---- epilogue (uniform across the wave) ----
  const float norm  = sqrtf(ss) + EPSF;
  const float inv2n = 0.5f / norm;
  const float i2    = inv2n * inv2n;
  // Z = sum exp(x), Zm = sum exp(-x), Taylor in moments (|x| <= ~0.05):
  const float t1 = sp * inv2n;
  const float t2 = 0.5f * ss * i2;
  const float t3 = (1.0f / 6.0f) * sc * i2 * inv2n;
  const float t4 = (1.0f / 24.0f) * sq * i2 * i2;
  const float Z    = (float)NC + t1 + t2 + t3 + t4;
  const float Zm   = (float)NC - t1 + t2 - t3 + t4;
  const float logZ = logf(Z);
  const float eZ   = EPSF * Z;

  const float max_prob = __expf(mv * inv2n) / Z + EPSF;
  // amax == lab  <=>  p[lab] attains the row max (ties measure-zero for normals)
  const bool  replace  = (ru <= max_prob) && (mv != p_lab);
  const float p_neg    = replace ? mv : p_c1;      // p[amax] == mv when replaced

  // log(snorm_j + eps) = x_j + log1p(eZ e^{-x_j}) - logZ ~= x_j + eZ(1 - x_j) - logZ
  const float x_lab  = p_lab * inv2n;
  const float x_neg  = p_neg * inv2n;
  const float ls_lab = x_lab + eZ * (1.0f - x_lab) - logZ;
  const float ls_neg = x_neg + eZ * (1.0f - x_neg) - logZ;
  const float sumlog = t1 + eZ * Zm - (float)NC * logZ;   // sum_j log(snorm_j+eps)

  if (lane == 0) {
    out[1 + row] = norm;
    row_acc[row] = (sumlog - ls_lab) - ls_neg;
  }
}

__global__ __launch_bounds__(512)
void nnce_final(const float* __restrict__ row_acc, float* __restrict__ out) {
  __shared__ double lred[8];
  const int tid  = threadIdx.x;
  const int lane = tid & 63;
  const int wid  = tid >> 6;
  const float4* r4 = (const float4*)row_acc;   // 4096 float4
  double s = 0.0;
  for (int i = tid; i < NROWS / 4; i += 512) {
    const float4 v = r4[i];
    s += (double)v.x + (double)v.y + (double)v.z + (double)v.w;
  }
  for (int o = 32; o > 0; o >>= 1) s += __shfl_xor(s, o, 64);
  if (lane == 0) lred[wid] = s;
  __syncthreads();
  if (tid == 0) {
    double t = 0.0;
    for (int w = 0; w < 8; ++w) t += lred[w];
    out[0] = (float)(10.0 * t / (double)NROWS);
  }
}

extern "C" void kernel_launch(void* const* d_in, const int* in_sizes, int n_in,
                              void* d_out, int out_size, void* d_ws, size_t ws_size,
                              hipStream_t stream) {
  const float* pred   = (const float*)d_in[0];
  const int*   labels = (const int*)d_in[1];
  float* out     = (float*)d_out;
  float* row_acc = (float*)d_ws;   // 64 KB

  nnce_rows<<<NBLK, BLK, 0, stream>>>(pred, labels, out, row_acc);
  nnce_final<<<1, 512, 0, stream>>>(row_acc, out);
}